// Round 6
// baseline (1135.072 us; speedup 1.0000x reference)
//
#include <hip/hip_runtime.h>

typedef __attribute__((ext_vector_type(4))) float f32x4;
typedef __attribute__((ext_vector_type(8))) _Float16 f16x8;
typedef __attribute__((ext_vector_type(4))) _Float16 f16x4;

#define N_TOK 16384
#define DIM 1024
#define HID 2048
#define NE 8
#define CAP 4096

// async global->LDS, 16B per lane; LDS dest is wave-uniform base + lane*16
#define GLD_LDS16(gaddr, laddr)                                                   \
    __builtin_amdgcn_global_load_lds(                                             \
        (const __attribute__((address_space(1))) void*)(gaddr),                   \
        (__attribute__((address_space(3))) void*)(laddr), 16, 0, 0)

// raw barrier with compiler-level memory fence (no vmcnt/lgkm drain emitted)
#define SBAR()                                     \
    do {                                           \
        asm volatile("" ::: "memory");             \
        __builtin_amdgcn_s_barrier();              \
        asm volatile("" ::: "memory");             \
    } while (0)

// ---------------- Router: scores^T (E, N) = softmax(x @ wg, axis=-1)^T -------
__global__ __launch_bounds__(256) void router_kernel(
    const float* __restrict__ x, const float* __restrict__ wg,
    float* __restrict__ scoresT)
{
    int t = blockIdx.x * 4 + (threadIdx.x >> 6);
    int lane = threadIdx.x & 63;
    const float* xr = x + (size_t)t * DIM;
    float acc[NE] = {};
    for (int k = lane; k < DIM; k += 64) {
        float xv = xr[k];
        const float4* w4 = (const float4*)(wg + (size_t)k * NE);
        float4 a = w4[0], b = w4[1];
        acc[0] += xv * a.x; acc[1] += xv * a.y; acc[2] += xv * a.z; acc[3] += xv * a.w;
        acc[4] += xv * b.x; acc[5] += xv * b.y; acc[6] += xv * b.z; acc[7] += xv * b.w;
    }
#pragma unroll
    for (int off = 32; off; off >>= 1)
#pragma unroll
        for (int e = 0; e < NE; ++e) acc[e] += __shfl_xor(acc[e], off);
    if (lane == 0) {
        float m = acc[0];
#pragma unroll
        for (int e = 1; e < NE; ++e) m = fmaxf(m, acc[e]);
        float p[NE]; float s = 0.f;
#pragma unroll
        for (int e = 0; e < NE; ++e) { p[e] = expf(acc[e] - m); s += p[e]; }
        float inv = 1.0f / s;
#pragma unroll
        for (int e = 0; e < NE; ++e) scoresT[(size_t)e * N_TOK + t] = p[e] * inv;
    }
}

// ---- Top-k pass 1: global 65536-bin histogram of top-16 key bits ----------
__global__ __launch_bounds__(256) void hist16_kernel(
    const float* __restrict__ scoresT, int* __restrict__ hist)
{
    int e = blockIdx.y;
    int t = blockIdx.x * 512 + threadIdx.x;
    const float* row = scoresT + (size_t)e * N_TOK;
    int* h = hist + (size_t)e * 65536;
#pragma unroll
    for (int i = 0; i < 2; ++i) {
        unsigned key = __float_as_uint(row[t + i * 256]);
        atomicAdd(&h[key >> 16], 1);
    }
}

// ---- Top-k pass 2: find threshold bin, strictly-above count, remaining ----
__global__ __launch_bounds__(256) void scan16_kernel(
    const int* __restrict__ hist, unsigned* __restrict__ prefix16,
    int* __restrict__ G16, int* __restrict__ rem)
{
    int e = blockIdx.x;
    const int* h = hist + (size_t)e * 65536;
    __shared__ int sums[256];
    __shared__ int bins[256];
    __shared__ int s_c, s_cum;
    int t = threadIdx.x;
    int s = 0;
    for (int b = 0; b < 256; ++b) s += h[t * 256 + b];
    sums[t] = s;
    __syncthreads();
    if (t == 0) {
        int cum = 0; int c = 255;
        for (; c >= 0; --c) {
            if (cum + sums[c] >= CAP) break;
            cum += sums[c];
        }
        s_c = c; s_cum = cum;
    }
    __syncthreads();
    bins[t] = h[s_c * 256 + t];
    __syncthreads();
    if (t == 0) {
        int cum = s_cum; int b = 255;
        for (; b >= 0; --b) {
            if (cum + bins[b] >= CAP) break;
            cum += bins[b];
        }
        prefix16[e] = (unsigned)(s_c * 256 + b);
        G16[e] = cum;            // strictly above threshold bin
        rem[e] = CAP - cum;      // to take from within the bin
    }
}

// ---- Top-k pass 3: fill strictly-above (order-free) + collect bin members -
__global__ __launch_bounds__(256) void fill_collect_kernel(
    const float* __restrict__ scoresT, const unsigned* __restrict__ prefix16,
    int* __restrict__ cnt, int* __restrict__ candcnt,
    int* __restrict__ idx, float* __restrict__ scale, unsigned* __restrict__ candbuf)
{
    int t = blockIdx.x * 256 + threadIdx.x;
    int e = blockIdx.y;
    float s = scoresT[(size_t)e * N_TOK + t];
    unsigned hi = __float_as_uint(s) >> 16;
    unsigned p16 = prefix16[e];
    if (hi > p16) {
        int pos = atomicAdd(&cnt[e], 1);
        idx[e * CAP + pos] = t;
        scale[e * CAP + pos] = s;
    } else if (hi == p16) {
        int pos = atomicAdd(&candcnt[e], 1);
        candbuf[(size_t)e * N_TOK + pos] =
            ((__float_as_uint(s) & 0xFFFFu) << 16) | (unsigned)(16383 - t);
    }
}

// ---- Top-k pass 4: rank in-bin candidates, keep top `rem` ------------------
__global__ __launch_bounds__(256) void cand_rank_kernel(
    const unsigned* __restrict__ prefix16, const int* __restrict__ G16,
    const int* __restrict__ rem, const int* __restrict__ candcnt,
    const unsigned* __restrict__ candbuf, int* __restrict__ idx, float* __restrict__ scale)
{
    int e = blockIdx.x;
    int Tc = candcnt[e], q = rem[e], g = G16[e];
    const unsigned* cb = candbuf + (size_t)e * N_TOK;
    for (int i = threadIdx.x; i < Tc; i += 256) {
        unsigned mine = cb[i];
        int rank = 0;
        for (int j = 0; j < Tc; ++j) rank += (cb[j] > mine) ? 1 : 0;
        if (rank < q) {
            int token = 16383 - (int)(mine & 0xFFFFu);
            unsigned keyfull = (prefix16[e] << 16) | (mine >> 16);
            idx[e * CAP + g + rank] = token;
            scale[e * CAP + g + rank] = __uint_as_float(keyfull);
        }
    }
}

// ---- Inverse index: token -> list of source rows (e*CAP+c), n<=8 ----------
__global__ __launch_bounds__(256) void inv_build_kernel(
    const int* __restrict__ idx, int* __restrict__ tokcnt, int* __restrict__ toklist)
{
    int i = blockIdx.x * 256 + threadIdx.x;    // over NE*CAP
    int token = idx[i];
    int p = atomicAdd(&tokcnt[token], 1);
    toklist[token * 8 + p] = i;
}

// ---- Combine: out[token] (+)= sum of this group's routed rows --------------
// rfmt: 0 = routed is f32, 1 = routed is f16
__global__ __launch_bounds__(256) void combine_kernel(
    const void* __restrict__ routedv, const int* __restrict__ tokcnt,
    const int* __restrict__ toklist, float* __restrict__ out,
    int e0, int g, int accum, int rfmt)
{
    int token = blockIdx.x * 4 + (threadIdx.x >> 6);
    int lane = threadIdx.x & 63;
    int n = tokcnt[token];
    f32x4* op = (f32x4*)(out + (size_t)token * DIM);
    f32x4 acc[4];
    if (accum) {
#pragma unroll
        for (int k = 0; k < 4; ++k) acc[k] = op[lane + 64 * k];
    } else {
#pragma unroll
        for (int k = 0; k < 4; ++k) acc[k] = (f32x4){0.f, 0.f, 0.f, 0.f};
    }
    for (int j = 0; j < n; ++j) {
        int src = toklist[token * 8 + j];
        int e = src >> 12;                      // CAP = 4096
        if (e < e0 || e >= e0 + g) continue;
        size_t row = (size_t)(src - (e0 << 12));
        if (rfmt == 0) {
            const f32x4* rp = (const f32x4*)((const float*)routedv + row * DIM);
#pragma unroll
            for (int k = 0; k < 4; ++k) acc[k] += rp[lane + 64 * k];
        } else {
            const f16x4* rp = (const f16x4*)((const _Float16*)routedv + row * DIM);
#pragma unroll
            for (int k = 0; k < 4; ++k) {
                f16x4 hv = rp[lane + 64 * k];
                acc[k][0] += (float)hv[0]; acc[k][1] += (float)hv[1];
                acc[k][2] += (float)hv[2]; acc[k][3] += (float)hv[3];
            }
        }
    }
#pragma unroll
    for (int k = 0; k < 4; ++k) op[lane + 64 * k] = acc[k];
}

// -------- Weight transpose+convert, all three weights in ONE dispatch -------
// blockIdx.z = z: e = z&7, m = z>>3 (0:w1 -> w13T even 32-groups,
// 1:w3 -> w13T odd 32-groups, 2:w2 -> w2T plain B^T).
__global__ __launch_bounds__(256) void transpose_convert_all_kernel(
    const float* __restrict__ w1, const float* __restrict__ w3,
    const float* __restrict__ w2, _Float16* __restrict__ w13T,
    _Float16* __restrict__ w2T)
{
    int z = blockIdx.z;
    int e = z & 7, m = z >> 3;
    int K = (m == 2) ? HID : DIM;
    int N = (m == 2) ? DIM : HID;
    int nbk = K >> 6;
    int k0 = (blockIdx.x & (nbk - 1)) * 64;         // nbk is power of 2
    int n0 = (blockIdx.x / nbk) * 64;
    const float* W = ((m == 0) ? w1 : (m == 1) ? w3 : w2) + (size_t)e * K * N;
    _Float16* WTb = (m == 2) ? (w2T + (size_t)e * DIM * HID)
                             : (w13T + (size_t)e * 2 * HID * DIM);
    __shared__ float tile[64][65];
#pragma unroll
    for (int i = 0; i < 16; ++i) {
        int lin = i * 256 + threadIdx.x;
        int r = lin >> 6, c = lin & 63;
        tile[r][c] = W[(size_t)(k0 + r) * N + n0 + c];
    }
    __syncthreads();
#pragma unroll
    for (int i = 0; i < 16; ++i) {
        int lin = i * 256 + threadIdx.x;
        int r = lin >> 6, c = lin & 63;   // r: n-offset, c: k-offset
        int n = n0 + r;
        int R;
        if (m == 2) R = n;
        else R = (n >> 7) * 256 + ((n >> 5) & 3) * 64 + ((m == 1) ? 32 : 0) + (n & 31);
        WTb[(size_t)R * K + k0 + c] = (_Float16)tile[c][r];
    }
}

// ---- Gather + scale + convert, batched: blockIdx.y = expert-in-group -------
__global__ __launch_bounds__(256) void gather_rows_kernel(
    const float* __restrict__ x, const int* __restrict__ idx,
    const float* __restrict__ scale, _Float16* __restrict__ Ae, int e0)
{
    int ez = blockIdx.y;
    int c = blockIdx.x;
    int token = idx[(e0 + ez) * CAP + c];
    float sc = scale[(e0 + ez) * CAP + c];
    const float4* xr = (const float4*)(x + (size_t)token * DIM);
    float4 v = xr[threadIdx.x];
    f16x4 h;
    h[0] = (_Float16)(v.x * sc); h[1] = (_Float16)(v.y * sc);
    h[2] = (_Float16)(v.z * sc); h[3] = (_Float16)(v.w * sc);
    *(f16x4*)(Ae + ((size_t)ez * CAP + c) * DIM + threadIdx.x * 4) = h;
}

// ============================================================================
// 256x256 GEMM core, 3-barrier-per-K-tile schedule (see R4 derivation).
// ============================================================================
template<int LD, int NT>
__device__ __forceinline__ void gemm256_loop(
    const _Float16* __restrict__ Ag,   // block A panel: 256 rows x LD
    const _Float16* __restrict__ Bg,   // block B panel: 256 rows x LD
    _Float16* lds, f32x4 (&acc)[8][4])
{
    const int tid  = threadIdx.x;
    const int lane = tid & 63;
    const int wid  = tid >> 6;
    const int lr = lane >> 3, lc = lane & 7;
    const int row16 = lane & 15, qi = lane >> 4, r7 = row16 & 7;
    const int wm = (wid >> 2) * 128;
    const int wn = (wid & 3) * 64;
    const int cls = wid >> 2;                               // 0: A-early, 1: B-early
    const int sa = (wid & 1) | ((wid & 2) << 1) | (cls << 1);   // A band
    const int sb = ((wid & 3) << 1) | (cls ^ 1);                // B band

    const _Float16* gA = Ag + (size_t)(sa * 32 + lr) * LD + (lc ^ lr) * 8;
    const _Float16* gB = Bg + (size_t)(sb * 32 + lr) * LD + (lc ^ lr) * 8;
    _Float16* lA0 = lds + sa * 32 * 64;                  // wave-uniform LDS bases
    _Float16* lB0 = lds + 16384 + sb * 32 * 64;

#define STG_A(T, i) GLD_LDS16(gA + (size_t)(i) * (8 * LD) + (T) * 64, lA0 + ((T) & 1) * 32768 + (i) * 512)
#define STG_B(T, i) GLD_LDS16(gB + (size_t)(i) * (8 * LD) + (T) * 64, lB0 + ((T) & 1) * 32768 + (i) * 512)
#define SLOT12(T) do { if (cls == 0) { STG_A(T, 0); STG_A(T, 1); } else { STG_B(T, 0); STG_B(T, 1); } } while (0)
#define SLOT34(T) do { if (cls == 0) { STG_A(T, 2); STG_A(T, 3); } else { STG_B(T, 2); STG_B(T, 3); } } while (0)
#define SLOT56(T) do { if (cls == 0) { STG_B(T, 0); STG_B(T, 1); } else { STG_A(T, 0); STG_A(T, 1); } } while (0)
#define SLOT78(T) do { if (cls == 0) { STG_B(T, 2); STG_B(T, 3); } else { STG_A(T, 2); STG_A(T, 3); } } while (0)

    const unsigned ldsb = (unsigned)(size_t)(const __attribute__((address_space(3))) _Float16*)lds;
    const unsigned aB = ldsb + (unsigned)((wm + row16) * 128);
    const unsigned bB = ldsb + 32768u + (unsigned)((wn + row16) * 128);
    const unsigned ck = (unsigned)((qi ^ r7) * 16);

#define DSR(dst, addr) asm volatile("ds_read_b128 %0, %1" : "=v"(dst) : "v"(addr))
#define A_ADDR(b, m, ks) (aB + (unsigned)(b) * 65536u + (unsigned)(m) * 2048u + (ck ^ ((unsigned)(ks) * 64u)))
#define B_ADDR(b, j, ks) (bB + (unsigned)(b) * 65536u + (unsigned)(j) * 2048u + (ck ^ ((unsigned)(ks) * 64u)))
#define MFMA16(a, b, c) __builtin_amdgcn_mfma_f32_16x16x32_f16(a, b, c, 0, 0, 0)
#define LGKM0() do { asm volatile("s_waitcnt lgkmcnt(0)" ::: "memory"); \
                     __builtin_amdgcn_sched_barrier(0); } while (0)

    // prologue: tile0 full (8 issues), tile1 first 6 (SLOT78(1) comes in tile0)
    SLOT12(0); SLOT34(0); SLOT56(0); SLOT78(0);
    SLOT12(1); SLOT34(1); SLOT56(1);
    asm volatile("s_waitcnt vmcnt(6)" ::: "memory");
    SBAR();

    f16x8 ar[4][2], br0[2][2], br1[2][2];

#pragma unroll 2
    for (int t = 0; t < NT; ++t) {
        const int b = t & 1;
        // ---- R0: A-low + B-low (12 reads); stage t+1's last 2 (buffer b^1)
#pragma unroll
        for (int m = 0; m < 4; ++m) { DSR(ar[m][0], A_ADDR(b, m, 0)); DSR(ar[m][1], A_ADDR(b, m, 1)); }
#pragma unroll
        for (int j = 0; j < 2; ++j) { DSR(br0[j][0], B_ADDR(b, j, 0)); DSR(br0[j][1], B_ADDR(b, j, 1)); }
        if (t + 1 < NT) SLOT78(t + 1);
        LGKM0();
        __builtin_amdgcn_s_setprio(1);
#pragma unroll
        for (int m = 0; m < 4; ++m)
#pragma unroll
            for (int j = 0; j < 2; ++j) {
                acc[m][j] = MFMA16(ar[m][0], br0[j][0], acc[m][j]);
                acc[m][j] = MFMA16(ar[m][1], br0[j][1], acc[m][j]);
            }
        __builtin_amdgcn_s_setprio(0);
        __builtin_amdgcn_sched_barrier(0);
        // ---- R1: B-high (4 reads), then B1 (all waves' R0 reads complete)
#pragma unroll
        for (int j = 0; j < 2; ++j) { DSR(br1[j][0], B_ADDR(b, 2 + j, 0)); DSR(br1[j][1], B_ADDR(b, 2 + j, 1)); }
        SBAR();                                   // B1
        if (t + 2 < NT) { SLOT12(t + 2); SLOT34(t + 2); }
        LGKM0();
        __builtin_amdgcn_s_setprio(1);
#pragma unroll
        for (int m = 0; m < 4; ++m)
#pragma unroll
            for (int j = 0; j < 2; ++j) {
                acc[m][2 + j] = MFMA16(ar[m][0], br1[j][0], acc[m][2 + j]);
                acc[m][2 + j] = MFMA16(ar[m][1], br1[j][1], acc[m][2 + j]);
            }
        __builtin_amdgcn_s_setprio(0);
        __builtin_amdgcn_sched_barrier(0);
        // ---- R2: A-high (8 reads, reuse ar regs)
#pragma unroll
        for (int m = 0; m < 4; ++m) { DSR(ar[m][0], A_ADDR(b, 4 + m, 0)); DSR(ar[m][1], A_ADDR(b, 4 + m, 1)); }
        LGKM0();
        __builtin_amdgcn_s_setprio(1);
#pragma unroll
        for (int m = 0; m < 4; ++m)
#pragma unroll
            for (int j = 0; j < 2; ++j) {
                acc[4 + m][j] = MFMA16(ar[m][0], br0[j][0], acc[4 + m][j]);
                acc[4 + m][j] = MFMA16(ar[m][1], br0[j][1], acc[4 + m][j]);
            }
        __builtin_amdgcn_s_setprio(0);
        __builtin_amdgcn_sched_barrier(0);
        SBAR();                                   // B2 (R1+R2 complete everywhere)
        if (t + 2 < NT) SLOT56(t + 2);
        __builtin_amdgcn_s_setprio(1);
#pragma unroll
        for (int m = 0; m < 4; ++m)
#pragma unroll
            for (int j = 0; j < 2; ++j) {
                acc[4 + m][2 + j] = MFMA16(ar[m][0], br1[j][0], acc[4 + m][2 + j]);
                acc[4 + m][2 + j] = MFMA16(ar[m][1], br1[j][1], acc[4 + m][2 + j]);
            }
        __builtin_amdgcn_s_setprio(0);
        __builtin_amdgcn_sched_barrier(0);
        if (t + 2 < NT) { asm volatile("s_waitcnt vmcnt(6)" ::: "memory"); }
        else            { asm volatile("s_waitcnt vmcnt(0)" ::: "memory"); }
        SBAR();                                   // B3 (t+1 fully in LDS)
    }
#undef STG_A
#undef STG_B
#undef SLOT12
#undef SLOT34
#undef SLOT56
#undef SLOT78
#undef DSR
#undef A_ADDR
#undef B_ADDR
#undef MFMA16
#undef LGKM0
}

// ---- GEMM13 + SwiGLU fused: H = silu(A@W1^T) * (A@W3^T), f16 out -----------
__global__ __launch_bounds__(512, 2) void gemm13_swiglu_kernel(
    const _Float16* __restrict__ Ae, const _Float16* __restrict__ w13T,
    _Float16* __restrict__ H, int e0)
{
    __shared__ _Float16 lds[65536];      // 128 KiB
    const int f = blockIdx.x;
    const int x = f & 7, s = f >> 3;
    const int ez = s >> 5;
    const int w = s & 31;
    const int bmI = (x & 3) * 4 + (w & 3);       // [0,16)
    const int bnI = (x >> 2) * 8 + (w >> 2);     // [0,16)

    const _Float16* Ag = Ae + (size_t)ez * CAP * DIM + (size_t)bmI * 256 * DIM;
    const _Float16* Bg = w13T + (size_t)(e0 + ez) * (2 * HID * DIM) + (size_t)bnI * 256 * DIM;

    f32x4 acc[8][4] = {};
    gemm256_loop<DIM, DIM / 64>(Ag, Bg, lds, acc);

    const int tid = threadIdx.x;
    const int lane = tid & 63, wid = tid >> 6;
    const int wm = (wid >> 2) * 128;
    const int q = wid & 3;
    const int col0 = lane & 15, r0 = (lane >> 4) * 4;
    _Float16* Hc = H + (size_t)ez * CAP * HID;
#pragma unroll
    for (int m = 0; m < 8; ++m)
#pragma unroll
        for (int r = 0; r < 4; ++r) {
            int row = bmI * 256 + wm + m * 16 + r0 + r;
#pragma unroll
            for (int jp = 0; jp < 2; ++jp) {
                float g1 = acc[m][jp][r];
                float g3 = acc[m][jp + 2][r];
                float sv = g1 / (1.0f + __expf(-g1)) * g3;
                Hc[(size_t)row * HID + bnI * 128 + q * 32 + jp * 16 + col0] = (_Float16)sv;
            }
        }
}

// ---- GEMM2, K-SPLIT: routed (+)= H[:, k0:k0+1024] @ W2^T[:, k0:k0+1024].
//  Two accumulating passes keep the per-XCD L2 working set at 6 MB (panels
//  0.5 MB) instead of 12 MB (K=2048 panels 1 MB) -> same regime as gemm13.
//  planA: pass accum=0 stores, accum=1 does exclusive-tile RMW (no atomics).
//  planB: f32 atomics straight into out (both passes).
__global__ __launch_bounds__(512, 2) void gemm2_scatter_kernel(
    const _Float16* __restrict__ H, const _Float16* __restrict__ w2T,
    float* __restrict__ out, const int* __restrict__ idx,
    void* __restrict__ routedv, int e0, int swz, int planA, int rfmt,
    int k0, int accum)
{
    __shared__ _Float16 lds[65536];      // 128 KiB
    const int f = blockIdx.x;
    int ez, bmI, bnI;
    if (swz) {        // valid for g in {4,8}: XCD x owns 8x4 rect; 2 XCDs/expert
        const int x = f & 7, s = f >> 3;
        ez = (x >> 1) + (s >> 5) * 4;
        const int w = s & 31;
        bmI = (x & 1) * 8 + (w & 7);
        bnI = (w >> 3) & 3;
    } else {
        ez = f >> 6;
        const int r = f & 63;
        bmI = r & 15;
        bnI = r >> 4;
    }
    const _Float16* Ag = H + (size_t)ez * CAP * HID + (size_t)bmI * 256 * HID + k0;
    const _Float16* Bg = w2T + (size_t)(e0 + ez) * DIM * HID + (size_t)bnI * 256 * HID + k0;

    f32x4 acc[8][4] = {};
    gemm256_loop<HID, HID / 128>(Ag, Bg, lds, acc);     // NT = 16 (K=1024 half)

    const int tid = threadIdx.x;
    const int lane = tid & 63, wid = tid >> 6;
    const int wm = (wid >> 2) * 128, wn = (wid & 3) * 64;
    const int col0 = lane & 15, r0 = (lane >> 4) * 4;
    if (planA) {
        if (rfmt == 0) {
            float* rb = (float*)routedv + (size_t)ez * CAP * DIM;
#pragma unroll
            for (int m = 0; m < 8; ++m)
#pragma unroll
                for (int r = 0; r < 4; ++r) {
                    int row = bmI * 256 + wm + m * 16 + r0 + r;
                    float* orow = rb + (size_t)row * DIM + bnI * 256 + wn + col0;
                    if (accum) {
#pragma unroll
                        for (int j = 0; j < 4; ++j)
                            orow[j * 16] = orow[j * 16] + acc[m][j][r];
                    } else {
#pragma unroll
                        for (int j = 0; j < 4; ++j)
                            orow[j * 16] = acc[m][j][r];
                    }
                }
        } else {
            _Float16* rb = (_Float16*)routedv + (size_t)ez * CAP * DIM;
#pragma unroll
            for (int m = 0; m < 8; ++m)
#pragma unroll
                for (int r = 0; r < 4; ++r) {
                    int row = bmI * 256 + wm + m * 16 + r0 + r;
                    _Float16* orow = rb + (size_t)row * DIM + bnI * 256 + wn + col0;
                    if (accum) {
#pragma unroll
                        for (int j = 0; j < 4; ++j)
                            orow[j * 16] = (_Float16)((float)orow[j * 16] + acc[m][j][r]);
                    } else {
#pragma unroll
                        for (int j = 0; j < 4; ++j)
                            orow[j * 16] = (_Float16)acc[m][j][r];
                    }
                }
        }
    } else {
        const int* rowidx = idx + (e0 + ez) * CAP;
#pragma unroll
        for (int m = 0; m < 8; ++m)
#pragma unroll
            for (int r = 0; r < 4; ++r) {
                int token = rowidx[bmI * 256 + wm + m * 16 + r0 + r];
                float* orow = out + (size_t)token * DIM + bnI * 256 + wn + col0;
#pragma unroll
                for (int j = 0; j < 4; ++j)
                    atomicAdd(orow + j * 16, acc[m][j][r]);
            }
    }
}

extern "C" void kernel_launch(void* const* d_in, const int* in_sizes, int n_in,
                              void* d_out, int out_size, void* d_ws, size_t ws_size,
                              hipStream_t stream)
{
    const float* x  = (const float*)d_in[0];
    const float* wg = (const float*)d_in[1];
    const float* w1 = (const float*)d_in[2];
    const float* w3 = (const float*)d_in[3];
    const float* w2 = (const float*)d_in[4];
    float* out = (float*)d_out;

    char* ws = (char*)d_ws;
    size_t off = 0;
    auto alloc = [&](size_t bytes) -> void* {
        void* p = ws + off;
        off += (bytes + 255) & ~(size_t)255;
        return p;
    };
    float*     scoresT  = (float*)alloc((size_t)NE * N_TOK * 4);
    int*       hist     = (int*)alloc((size_t)NE * 65536 * 4);     // 2 MB
    unsigned*  prefix16 = (unsigned*)alloc(256);
    int*       G16      = (int*)alloc(256);
    int*       rem      = (int*)alloc(256);
    int*       counters = (int*)alloc(256);      // [0..7]=cnt, [8..15]=candcnt
    int*       idx      = (int*)alloc((size_t)NE * CAP * 4);
    float*     scale    = (float*)alloc((size_t)NE * CAP * 4);
    unsigned*  candbuf  = (unsigned*)alloc((size_t)NE * N_TOK * 4);
    int*       tokcnt   = (int*)alloc((size_t)N_TOK * 4);          // 64 KB
    int*       toklist  = (int*)alloc((size_t)N_TOK * 8 * 4);      // 512 KB
    _Float16*  w13T     = (_Float16*)alloc((size_t)NE * 2 * HID * DIM * 2); // 64 MB
    _Float16*  w2T      = (_Float16*)alloc((size_t)NE * DIM * HID * 2);     // 32 MB
    int* cnt = counters;
    int* candcnt = counters + 8;

    // ---- Plan selection (depends only on ws_size: capture-safe) -----------
    // Per-expert sizes: Ae 8 MB (f16), H 16 MB (f16), routed 16 MB f32 / 8 MB f16.
    // routed ALIASES Ae (Ae is dead after gemm13 reads it).
    const size_t MBs = (size_t)1 << 20;
    int g, planA, rfmt;
    if      (off + 256 * MBs <= ws_size) { planA = 1; rfmt = 0; g = 8; }
    else if (off + 192 * MBs <= ws_size) { planA = 1; rfmt = 1; g = 8; }
    else if (off + 128 * MBs <= ws_size) { planA = 1; rfmt = 0; g = 4; }
    else if (off +  96 * MBs <= ws_size) { planA = 1; rfmt = 1; g = 4; }
    else {
        planA = 0; rfmt = 0; g = 2;
        while (g > 1 && off + (size_t)g * 24 * MBs > ws_size) g >>= 1;
    }
    _Float16* Ae = (_Float16*)alloc((size_t)g * CAP * DIM * 2);
    void* routedv = (void*)Ae;                       // alias (see above)
    if (planA && rfmt == 0)
        (void)alloc((size_t)g * CAP * DIM * 2);      // extension: f32 needs 2x
    _Float16* H  = (_Float16*)alloc((size_t)g * CAP * HID * 2);

    hipMemsetAsync(d_out, 0, (size_t)out_size * 4, stream);
    hipMemsetAsync(counters, 0, 256, stream);
    hipMemsetAsync(hist, 0, (size_t)NE * 65536 * 4, stream);
    if (planA) hipMemsetAsync(tokcnt, 0, (size_t)N_TOK * 4, stream);

    router_kernel<<<N_TOK / 4, 256, 0, stream>>>(x, wg, scoresT);
    hist16_kernel<<<dim3(N_TOK / 512, NE), 256, 0, stream>>>(scoresT, hist);
    scan16_kernel<<<NE, 256, 0, stream>>>(hist, prefix16, G16, rem);
    fill_collect_kernel<<<dim3(N_TOK / 256, NE), 256, 0, stream>>>(
        scoresT, prefix16, cnt, candcnt, idx, scale, candbuf);
    cand_rank_kernel<<<NE, 256, 0, stream>>>(prefix16, G16, rem, candcnt, candbuf, idx, scale);
    if (planA)
        inv_build_kernel<<<NE * CAP / 256, 256, 0, stream>>>(idx, tokcnt, toklist);

    // single dispatch: w1 -> even 32-col groups, w3 -> odd, w2 -> plain B^T
    transpose_convert_all_kernel<<<dim3(512, 1, 24), 256, 0, stream>>>(
        w1, w3, w2, w13T, w2T);

    for (int e0 = 0; e0 < NE; e0 += g) {
        gather_rows_kernel<<<dim3(CAP, g), 256, 0, stream>>>(x, idx, scale, Ae, e0);
        gemm13_swiglu_kernel<<<dim3(256 * g), 512, 0, stream>>>(Ae, w13T, H, e0);
        gemm2_scatter_kernel<<<dim3(64 * g), 512, 0, stream>>>(
            H, w2T, out, idx, routedv, e0, (g >= 4) ? 1 : 0, planA, rfmt, 0, 0);
        gemm2_scatter_kernel<<<dim3(64 * g), 512, 0, stream>>>(
            H, w2T, out, idx, routedv, e0, (g >= 4) ? 1 : 0, planA, rfmt, HID / 2, 1);
        if (planA)
            combine_kernel<<<N_TOK / 4, 256, 0, stream>>>(
                routedv, tokcnt, toklist, out, e0, g, e0 != 0 ? 1 : 0, rfmt);
    }
}

// Round 7
// 846.344 us; speedup vs baseline: 1.3411x; 1.3411x over previous
//
#include <hip/hip_runtime.h>

typedef __attribute__((ext_vector_type(4))) float f32x4;
typedef __attribute__((ext_vector_type(8))) _Float16 f16x8;
typedef __attribute__((ext_vector_type(4))) _Float16 f16x4;

#define N_TOK 16384
#define DIM 1024
#define HID 2048
#define NE 8
#define CAP 4096

// async global->LDS, 16B per lane; LDS dest is wave-uniform base + lane*16
#define GLD_LDS16(gaddr, laddr)                                                   \
    __builtin_amdgcn_global_load_lds(                                             \
        (const __attribute__((address_space(1))) void*)(gaddr),                   \
        (__attribute__((address_space(3))) void*)(laddr), 16, 0, 0)

// raw barrier with compiler-level memory fence (no vmcnt/lgkm drain emitted)
#define SBAR()                                     \
    do {                                           \
        asm volatile("" ::: "memory");             \
        __builtin_amdgcn_s_barrier();              \
        asm volatile("" ::: "memory");             \
    } while (0)

// ---------------- Router: scores^T (E, N) = softmax(x @ wg, axis=-1)^T -------
__global__ __launch_bounds__(256) void router_kernel(
    const float* __restrict__ x, const float* __restrict__ wg,
    float* __restrict__ scoresT)
{
    int t = blockIdx.x * 4 + (threadIdx.x >> 6);
    int lane = threadIdx.x & 63;
    const float* xr = x + (size_t)t * DIM;
    float acc[NE] = {};
    for (int k = lane; k < DIM; k += 64) {
        float xv = xr[k];
        const float4* w4 = (const float4*)(wg + (size_t)k * NE);
        float4 a = w4[0], b = w4[1];
        acc[0] += xv * a.x; acc[1] += xv * a.y; acc[2] += xv * a.z; acc[3] += xv * a.w;
        acc[4] += xv * b.x; acc[5] += xv * b.y; acc[6] += xv * b.z; acc[7] += xv * b.w;
    }
#pragma unroll
    for (int off = 32; off; off >>= 1)
#pragma unroll
        for (int e = 0; e < NE; ++e) acc[e] += __shfl_xor(acc[e], off);
    if (lane == 0) {
        float m = acc[0];
#pragma unroll
        for (int e = 1; e < NE; ++e) m = fmaxf(m, acc[e]);
        float p[NE]; float s = 0.f;
#pragma unroll
        for (int e = 0; e < NE; ++e) { p[e] = expf(acc[e] - m); s += p[e]; }
        float inv = 1.0f / s;
#pragma unroll
        for (int e = 0; e < NE; ++e) scoresT[(size_t)e * N_TOK + t] = p[e] * inv;
    }
}

// ---- Top-k pass 1: global 65536-bin histogram of top-16 key bits ----------
__global__ __launch_bounds__(256) void hist16_kernel(
    const float* __restrict__ scoresT, int* __restrict__ hist)
{
    int e = blockIdx.y;
    int t = blockIdx.x * 512 + threadIdx.x;
    const float* row = scoresT + (size_t)e * N_TOK;
    int* h = hist + (size_t)e * 65536;
#pragma unroll
    for (int i = 0; i < 2; ++i) {
        unsigned key = __float_as_uint(row[t + i * 256]);
        atomicAdd(&h[key >> 16], 1);
    }
}

// ---- Top-k pass 2: find threshold bin, strictly-above count, remaining ----
__global__ __launch_bounds__(256) void scan16_kernel(
    const int* __restrict__ hist, unsigned* __restrict__ prefix16,
    int* __restrict__ G16, int* __restrict__ rem)
{
    int e = blockIdx.x;
    const int* h = hist + (size_t)e * 65536;
    __shared__ int sums[256];
    __shared__ int bins[256];
    __shared__ int s_c, s_cum;
    int t = threadIdx.x;
    int s = 0;
    for (int b = 0; b < 256; ++b) s += h[t * 256 + b];
    sums[t] = s;
    __syncthreads();
    if (t == 0) {
        int cum = 0; int c = 255;
        for (; c >= 0; --c) {
            if (cum + sums[c] >= CAP) break;
            cum += sums[c];
        }
        s_c = c; s_cum = cum;
    }
    __syncthreads();
    bins[t] = h[s_c * 256 + t];
    __syncthreads();
    if (t == 0) {
        int cum = s_cum; int b = 255;
        for (; b >= 0; --b) {
            if (cum + bins[b] >= CAP) break;
            cum += bins[b];
        }
        prefix16[e] = (unsigned)(s_c * 256 + b);
        G16[e] = cum;            // strictly above threshold bin
        rem[e] = CAP - cum;      // to take from within the bin
    }
}

// ---- Top-k pass 3: fill strictly-above (order-free) + collect bin members -
__global__ __launch_bounds__(256) void fill_collect_kernel(
    const float* __restrict__ scoresT, const unsigned* __restrict__ prefix16,
    int* __restrict__ cnt, int* __restrict__ candcnt,
    int* __restrict__ idx, float* __restrict__ scale, unsigned* __restrict__ candbuf)
{
    int t = blockIdx.x * 256 + threadIdx.x;
    int e = blockIdx.y;
    float s = scoresT[(size_t)e * N_TOK + t];
    unsigned hi = __float_as_uint(s) >> 16;
    unsigned p16 = prefix16[e];
    if (hi > p16) {
        int pos = atomicAdd(&cnt[e], 1);
        idx[e * CAP + pos] = t;
        scale[e * CAP + pos] = s;
    } else if (hi == p16) {
        int pos = atomicAdd(&candcnt[e], 1);
        candbuf[(size_t)e * N_TOK + pos] =
            ((__float_as_uint(s) & 0xFFFFu) << 16) | (unsigned)(16383 - t);
    }
}

// ---- Top-k pass 4: rank in-bin candidates, keep top `rem` ------------------
__global__ __launch_bounds__(256) void cand_rank_kernel(
    const unsigned* __restrict__ prefix16, const int* __restrict__ G16,
    const int* __restrict__ rem, const int* __restrict__ candcnt,
    const unsigned* __restrict__ candbuf, int* __restrict__ idx, float* __restrict__ scale)
{
    int e = blockIdx.x;
    int Tc = candcnt[e], q = rem[e], g = G16[e];
    const unsigned* cb = candbuf + (size_t)e * N_TOK;
    for (int i = threadIdx.x; i < Tc; i += 256) {
        unsigned mine = cb[i];
        int rank = 0;
        for (int j = 0; j < Tc; ++j) rank += (cb[j] > mine) ? 1 : 0;
        if (rank < q) {
            int token = 16383 - (int)(mine & 0xFFFFu);
            unsigned keyfull = (prefix16[e] << 16) | (mine >> 16);
            idx[e * CAP + g + rank] = token;
            scale[e * CAP + g + rank] = __uint_as_float(keyfull);
        }
    }
}

// ---- Inverse index: token -> list of source rows (e*CAP+c), n<=8 ----------
__global__ __launch_bounds__(256) void inv_build_kernel(
    const int* __restrict__ idx, int* __restrict__ tokcnt, int* __restrict__ toklist)
{
    int i = blockIdx.x * 256 + threadIdx.x;    // over NE*CAP
    int token = idx[i];
    int p = atomicAdd(&tokcnt[token], 1);
    toklist[token * 8 + p] = i;
}

// ---- Combine: out[token] (+)= sum of this group's routed rows --------------
// rfmt: 0 = routed is f32, 1 = routed is f16
__global__ __launch_bounds__(256) void combine_kernel(
    const void* __restrict__ routedv, const int* __restrict__ tokcnt,
    const int* __restrict__ toklist, float* __restrict__ out,
    int e0, int g, int accum, int rfmt)
{
    int token = blockIdx.x * 4 + (threadIdx.x >> 6);
    int lane = threadIdx.x & 63;
    int n = tokcnt[token];
    f32x4* op = (f32x4*)(out + (size_t)token * DIM);
    f32x4 acc[4];
    if (accum) {
#pragma unroll
        for (int k = 0; k < 4; ++k) acc[k] = op[lane + 64 * k];
    } else {
#pragma unroll
        for (int k = 0; k < 4; ++k) acc[k] = (f32x4){0.f, 0.f, 0.f, 0.f};
    }
    for (int j = 0; j < n; ++j) {
        int src = toklist[token * 8 + j];
        int e = src >> 12;                      // CAP = 4096
        if (e < e0 || e >= e0 + g) continue;
        size_t row = (size_t)(src - (e0 << 12));
        if (rfmt == 0) {
            const f32x4* rp = (const f32x4*)((const float*)routedv + row * DIM);
#pragma unroll
            for (int k = 0; k < 4; ++k) acc[k] += rp[lane + 64 * k];
        } else {
            const f16x4* rp = (const f16x4*)((const _Float16*)routedv + row * DIM);
#pragma unroll
            for (int k = 0; k < 4; ++k) {
                f16x4 hv = rp[lane + 64 * k];
                acc[k][0] += (float)hv[0]; acc[k][1] += (float)hv[1];
                acc[k][2] += (float)hv[2]; acc[k][3] += (float)hv[3];
            }
        }
    }
#pragma unroll
    for (int k = 0; k < 4; ++k) op[lane + 64 * k] = acc[k];
}

// -------- Weight transpose+convert, all three weights in ONE dispatch -------
// blockIdx.z = z: e = z&7, m = z>>3 (0:w1 -> w13T even 32-groups,
// 1:w3 -> w13T odd 32-groups, 2:w2 -> w2T plain B^T).
__global__ __launch_bounds__(256) void transpose_convert_all_kernel(
    const float* __restrict__ w1, const float* __restrict__ w3,
    const float* __restrict__ w2, _Float16* __restrict__ w13T,
    _Float16* __restrict__ w2T)
{
    int z = blockIdx.z;
    int e = z & 7, m = z >> 3;
    int K = (m == 2) ? HID : DIM;
    int N = (m == 2) ? DIM : HID;
    int nbk = K >> 6;
    int k0 = (blockIdx.x & (nbk - 1)) * 64;         // nbk is power of 2
    int n0 = (blockIdx.x / nbk) * 64;
    const float* W = ((m == 0) ? w1 : (m == 1) ? w3 : w2) + (size_t)e * K * N;
    _Float16* WTb = (m == 2) ? (w2T + (size_t)e * DIM * HID)
                             : (w13T + (size_t)e * 2 * HID * DIM);
    __shared__ float tile[64][65];
#pragma unroll
    for (int i = 0; i < 16; ++i) {
        int lin = i * 256 + threadIdx.x;
        int r = lin >> 6, c = lin & 63;
        tile[r][c] = W[(size_t)(k0 + r) * N + n0 + c];
    }
    __syncthreads();
#pragma unroll
    for (int i = 0; i < 16; ++i) {
        int lin = i * 256 + threadIdx.x;
        int r = lin >> 6, c = lin & 63;   // r: n-offset, c: k-offset
        int n = n0 + r;
        int R;
        if (m == 2) R = n;
        else R = (n >> 7) * 256 + ((n >> 5) & 3) * 64 + ((m == 1) ? 32 : 0) + (n & 31);
        WTb[(size_t)R * K + k0 + c] = (_Float16)tile[c][r];
    }
}

// ---- Gather + scale + convert, batched: blockIdx.y = expert-in-group -------
__global__ __launch_bounds__(256) void gather_rows_kernel(
    const float* __restrict__ x, const int* __restrict__ idx,
    const float* __restrict__ scale, _Float16* __restrict__ Ae, int e0)
{
    int ez = blockIdx.y;
    int c = blockIdx.x;
    int token = idx[(e0 + ez) * CAP + c];
    float sc = scale[(e0 + ez) * CAP + c];
    const float4* xr = (const float4*)(x + (size_t)token * DIM);
    float4 v = xr[threadIdx.x];
    f16x4 h;
    h[0] = (_Float16)(v.x * sc); h[1] = (_Float16)(v.y * sc);
    h[2] = (_Float16)(v.z * sc); h[3] = (_Float16)(v.w * sc);
    *(f16x4*)(Ae + ((size_t)ez * CAP + c) * DIM + threadIdx.x * 4) = h;
}

// ============================================================================
// 256x256 GEMM core, 3-barrier-per-K-tile, COMPILER-SCHEDULED LDS reads.
// R6 post-mortem: three asm-rigid schedules all tied at 605 TF -> the
// {reads -> lgkmcnt(0) -> MFMA} per-phase serialization was the invariant.
// Here LDS reads are plain AS(3) C++ loads: hipcc emits counted lgkmcnt and
// interleaves ds_read with MFMA (m97 evidence). Hazard frontier unchanged:
// every staged-over band's reads are value-consumed by MFMAs that precede
// the barrier after which the staging is issued; s_barrier builtin is a full
// scheduling fence, so those waits cannot sink past it.
// ============================================================================
template<int LD, int NT>
__device__ __forceinline__ void gemm256_loop(
    const _Float16* __restrict__ Ag,   // block A panel: 256 rows x LD
    const _Float16* __restrict__ Bg,   // block B panel: 256 rows x LD
    _Float16* lds, f32x4 (&acc)[8][4])
{
    const int tid  = threadIdx.x;
    const int lane = tid & 63;
    const int wid  = tid >> 6;
    const int lr = lane >> 3, lc = lane & 7;
    const int row16 = lane & 15, qi = lane >> 4, r7 = row16 & 7;
    const int wm = (wid >> 2) * 128;
    const int wn = (wid & 3) * 64;
    const int cls = wid >> 2;                               // 0: A-early, 1: B-early
    const int sa = (wid & 1) | ((wid & 2) << 1) | (cls << 1);   // A band
    const int sb = ((wid & 3) << 1) | (cls ^ 1);                // B band

    const _Float16* gA = Ag + (size_t)(sa * 32 + lr) * LD + (lc ^ lr) * 8;
    const _Float16* gB = Bg + (size_t)(sb * 32 + lr) * LD + (lc ^ lr) * 8;
    _Float16* lA0 = lds + sa * 32 * 64;                  // wave-uniform LDS bases
    _Float16* lB0 = lds + 16384 + sb * 32 * 64;

#define STG_A(T, i) GLD_LDS16(gA + (size_t)(i) * (8 * LD) + (T) * 64, lA0 + ((T) & 1) * 32768 + (i) * 512)
#define STG_B(T, i) GLD_LDS16(gB + (size_t)(i) * (8 * LD) + (T) * 64, lB0 + ((T) & 1) * 32768 + (i) * 512)
#define SLOT12(T) do { if (cls == 0) { STG_A(T, 0); STG_A(T, 1); } else { STG_B(T, 0); STG_B(T, 1); } } while (0)
#define SLOT34(T) do { if (cls == 0) { STG_A(T, 2); STG_A(T, 3); } else { STG_B(T, 2); STG_B(T, 3); } } while (0)
#define SLOT56(T) do { if (cls == 0) { STG_B(T, 0); STG_B(T, 1); } else { STG_A(T, 0); STG_A(T, 1); } } while (0)
#define SLOT78(T) do { if (cls == 0) { STG_B(T, 2); STG_B(T, 3); } else { STG_A(T, 2); STG_A(T, 3); } } while (0)

    // AS(3) element-index reads; swizzled col group = (4*ks + qi) ^ r7,
    // identical permutation to the (lc ^ lr) pre-swizzled staging source.
    typedef __attribute__((address_space(3))) const _Float16 lds3_t;
    lds3_t* l3 = (lds3_t*)lds;
    const int aBe = (wm + row16) * 64;            // A row base (elems)
    const int bBe = 16384 + (wn + row16) * 64;    // B row base (elems)

#define A_ELEM(b, m, ks) ((b) * 32768 + aBe + (m) * 1024 + ((((ks) * 4 + qi) ^ r7) * 8))
#define B_ELEM(b, j, ks) ((b) * 32768 + bBe + (j) * 1024 + ((((ks) * 4 + qi) ^ r7) * 8))
#define LD8(idx) (*(const __attribute__((address_space(3))) f16x8*)(l3 + (idx)))
#define MFMA16(a, b, c) __builtin_amdgcn_mfma_f32_16x16x32_f16(a, b, c, 0, 0, 0)

    // prologue: tile0 full (8 issues), tile1 first 6 (SLOT78(1) comes in tile0)
    SLOT12(0); SLOT34(0); SLOT56(0); SLOT78(0);
    SLOT12(1); SLOT34(1); SLOT56(1);
    asm volatile("s_waitcnt vmcnt(6)" ::: "memory");
    SBAR();

#pragma unroll 2
    for (int t = 0; t < NT; ++t) {
        const int b = t & 1;
        f16x8 ar[4][2], ah[4][2], br0[2][2], br1[2][2];
        // ---- R0: A-low + B-low; stage t+1's last 2 (buffer b^1)
#pragma unroll
        for (int m = 0; m < 4; ++m) { ar[m][0] = LD8(A_ELEM(b, m, 0)); ar[m][1] = LD8(A_ELEM(b, m, 1)); }
#pragma unroll
        for (int j = 0; j < 2; ++j) { br0[j][0] = LD8(B_ELEM(b, j, 0)); br0[j][1] = LD8(B_ELEM(b, j, 1)); }
        if (t + 1 < NT) SLOT78(t + 1);
        // Q0 (consumes all R0 reads -> waits inserted before B1)
#pragma unroll
        for (int m = 0; m < 4; ++m)
#pragma unroll
            for (int j = 0; j < 2; ++j) {
                acc[m][j] = MFMA16(ar[m][0], br0[j][0], acc[m][j]);
                acc[m][j] = MFMA16(ar[m][1], br0[j][1], acc[m][j]);
            }
        // ---- R1: B-high
#pragma unroll
        for (int j = 0; j < 2; ++j) { br1[j][0] = LD8(B_ELEM(b, 2 + j, 0)); br1[j][1] = LD8(B_ELEM(b, 2 + j, 1)); }
        SBAR();                                   // B1: all waves' R0 reads done
        if (t + 2 < NT) { SLOT12(t + 2); SLOT34(t + 2); }
        // Q1 (consumes br1 before B2)
#pragma unroll
        for (int m = 0; m < 4; ++m)
#pragma unroll
            for (int j = 0; j < 2; ++j) {
                acc[m][2 + j] = MFMA16(ar[m][0], br1[j][0], acc[m][2 + j]);
                acc[m][2 + j] = MFMA16(ar[m][1], br1[j][1], acc[m][2 + j]);
            }
        // ---- R2: A-high (own regs -> compiler may hoist under Q0/Q1)
#pragma unroll
        for (int m = 0; m < 4; ++m) { ah[m][0] = LD8(A_ELEM(b, 4 + m, 0)); ah[m][1] = LD8(A_ELEM(b, 4 + m, 1)); }
        // Q2
#pragma unroll
        for (int m = 0; m < 4; ++m)
#pragma unroll
            for (int j = 0; j < 2; ++j) {
                acc[4 + m][j] = MFMA16(ah[m][0], br0[j][0], acc[4 + m][j]);
                acc[4 + m][j] = MFMA16(ah[m][1], br0[j][1], acc[4 + m][j]);
            }
        SBAR();                                   // B2: R1+R2 reads done everywhere
        if (t + 2 < NT) SLOT56(t + 2);
        // Q3 (registers only)
#pragma unroll
        for (int m = 0; m < 4; ++m)
#pragma unroll
            for (int j = 0; j < 2; ++j) {
                acc[4 + m][2 + j] = MFMA16(ah[m][0], br1[j][0], acc[4 + m][2 + j]);
                acc[4 + m][2 + j] = MFMA16(ah[m][1], br1[j][1], acc[4 + m][2 + j]);
            }
        if (t + 2 < NT) { asm volatile("s_waitcnt vmcnt(6)" ::: "memory"); }
        else            { asm volatile("s_waitcnt vmcnt(0)" ::: "memory"); }
        SBAR();                                   // B3: t+1 fully in LDS
    }
#undef STG_A
#undef STG_B
#undef SLOT12
#undef SLOT34
#undef SLOT56
#undef SLOT78
#undef A_ELEM
#undef B_ELEM
#undef LD8
#undef MFMA16
}

// ---- GEMM13 + SwiGLU fused: H = silu(A@W1^T) * (A@W3^T), f16 out -----------
__global__ __launch_bounds__(512, 2) void gemm13_swiglu_kernel(
    const _Float16* __restrict__ Ae, const _Float16* __restrict__ w13T,
    _Float16* __restrict__ H, int e0)
{
    __shared__ _Float16 lds[65536];      // 128 KiB
    const int f = blockIdx.x;
    const int x = f & 7, s = f >> 3;
    const int ez = s >> 5;
    const int w = s & 31;
    const int bmI = (x & 3) * 4 + (w & 3);       // [0,16)
    const int bnI = (x >> 2) * 8 + (w >> 2);     // [0,16)

    const _Float16* Ag = Ae + (size_t)ez * CAP * DIM + (size_t)bmI * 256 * DIM;
    const _Float16* Bg = w13T + (size_t)(e0 + ez) * (2 * HID * DIM) + (size_t)bnI * 256 * DIM;

    f32x4 acc[8][4] = {};
    gemm256_loop<DIM, DIM / 64>(Ag, Bg, lds, acc);

    const int tid = threadIdx.x;
    const int lane = tid & 63, wid = tid >> 6;
    const int wm = (wid >> 2) * 128;
    const int q = wid & 3;
    const int col0 = lane & 15, r0 = (lane >> 4) * 4;
    _Float16* Hc = H + (size_t)ez * CAP * HID;
#pragma unroll
    for (int m = 0; m < 8; ++m)
#pragma unroll
        for (int r = 0; r < 4; ++r) {
            int row = bmI * 256 + wm + m * 16 + r0 + r;
#pragma unroll
            for (int jp = 0; jp < 2; ++jp) {
                float g1 = acc[m][jp][r];
                float g3 = acc[m][jp + 2][r];
                float sv = g1 / (1.0f + __expf(-g1)) * g3;
                Hc[(size_t)row * HID + bnI * 128 + q * 32 + jp * 16 + col0] = (_Float16)sv;
            }
        }
}

// ---- GEMM2 (single pass, K=2048): routed = H @ W2^T.
//  planA: coalesced stores to `routed` (rfmt 0=f32, 1=f16), combined later.
//  planB: f32 atomics straight into out.
__global__ __launch_bounds__(512, 2) void gemm2_scatter_kernel(
    const _Float16* __restrict__ H, const _Float16* __restrict__ w2T,
    float* __restrict__ out, const int* __restrict__ idx,
    void* __restrict__ routedv, int e0, int swz, int planA, int rfmt)
{
    __shared__ _Float16 lds[65536];      // 128 KiB
    const int f = blockIdx.x;
    int ez, bmI, bnI;
    if (swz) {        // valid for g in {4,8}: XCD x owns 8x4 rect; 2 XCDs/expert
        const int x = f & 7, s = f >> 3;
        ez = (x >> 1) + (s >> 5) * 4;
        const int w = s & 31;
        bmI = (x & 1) * 8 + (w & 7);
        bnI = (w >> 3) & 3;
    } else {
        ez = f >> 6;
        const int r = f & 63;
        bmI = r & 15;
        bnI = r >> 4;
    }
    const _Float16* Ag = H + (size_t)ez * CAP * HID + (size_t)bmI * 256 * HID;
    const _Float16* Bg = w2T + (size_t)(e0 + ez) * DIM * HID + (size_t)bnI * 256 * HID;

    f32x4 acc[8][4] = {};
    gemm256_loop<HID, HID / 64>(Ag, Bg, lds, acc);

    const int tid = threadIdx.x;
    const int lane = tid & 63, wid = tid >> 6;
    const int wm = (wid >> 2) * 128, wn = (wid & 3) * 64;
    const int col0 = lane & 15, r0 = (lane >> 4) * 4;
    if (planA) {
        if (rfmt == 0) {
            float* rb = (float*)routedv + (size_t)ez * CAP * DIM;
#pragma unroll
            for (int m = 0; m < 8; ++m)
#pragma unroll
                for (int r = 0; r < 4; ++r) {
                    int row = bmI * 256 + wm + m * 16 + r0 + r;
                    float* orow = rb + (size_t)row * DIM + bnI * 256 + wn + col0;
#pragma unroll
                    for (int j = 0; j < 4; ++j)
                        orow[j * 16] = acc[m][j][r];
                }
        } else {
            _Float16* rb = (_Float16*)routedv + (size_t)ez * CAP * DIM;
#pragma unroll
            for (int m = 0; m < 8; ++m)
#pragma unroll
                for (int r = 0; r < 4; ++r) {
                    int row = bmI * 256 + wm + m * 16 + r0 + r;
                    _Float16* orow = rb + (size_t)row * DIM + bnI * 256 + wn + col0;
#pragma unroll
                    for (int j = 0; j < 4; ++j)
                        orow[j * 16] = (_Float16)acc[m][j][r];
                }
        }
    } else {
        const int* rowidx = idx + (e0 + ez) * CAP;
#pragma unroll
        for (int m = 0; m < 8; ++m)
#pragma unroll
            for (int r = 0; r < 4; ++r) {
                int token = rowidx[bmI * 256 + wm + m * 16 + r0 + r];
                float* orow = out + (size_t)token * DIM + bnI * 256 + wn + col0;
#pragma unroll
                for (int j = 0; j < 4; ++j)
                    atomicAdd(orow + j * 16, acc[m][j][r]);
            }
    }
}

extern "C" void kernel_launch(void* const* d_in, const int* in_sizes, int n_in,
                              void* d_out, int out_size, void* d_ws, size_t ws_size,
                              hipStream_t stream)
{
    const float* x  = (const float*)d_in[0];
    const float* wg = (const float*)d_in[1];
    const float* w1 = (const float*)d_in[2];
    const float* w3 = (const float*)d_in[3];
    const float* w2 = (const float*)d_in[4];
    float* out = (float*)d_out;

    char* ws = (char*)d_ws;
    size_t off = 0;
    auto alloc = [&](size_t bytes) -> void* {
        void* p = ws + off;
        off += (bytes + 255) & ~(size_t)255;
        return p;
    };
    float*     scoresT  = (float*)alloc((size_t)NE * N_TOK * 4);
    int*       hist     = (int*)alloc((size_t)NE * 65536 * 4);     // 2 MB
    unsigned*  prefix16 = (unsigned*)alloc(256);
    int*       G16      = (int*)alloc(256);
    int*       rem      = (int*)alloc(256);
    int*       counters = (int*)alloc(256);      // [0..7]=cnt, [8..15]=candcnt
    int*       idx      = (int*)alloc((size_t)NE * CAP * 4);
    float*     scale    = (float*)alloc((size_t)NE * CAP * 4);
    unsigned*  candbuf  = (unsigned*)alloc((size_t)NE * N_TOK * 4);
    int*       tokcnt   = (int*)alloc((size_t)N_TOK * 4);          // 64 KB
    int*       toklist  = (int*)alloc((size_t)N_TOK * 8 * 4);      // 512 KB
    _Float16*  w13T     = (_Float16*)alloc((size_t)NE * 2 * HID * DIM * 2); // 64 MB
    _Float16*  w2T      = (_Float16*)alloc((size_t)NE * DIM * HID * 2);     // 32 MB
    int* cnt = counters;
    int* candcnt = counters + 8;

    // ---- Plan selection (depends only on ws_size: capture-safe) -----------
    // Per-expert sizes: Ae 8 MB (f16), H 16 MB (f16), routed 16 MB f32 / 8 MB f16.
    // routed ALIASES Ae (Ae is dead after gemm13 reads it).
    const size_t MBs = (size_t)1 << 20;
    int g, planA, rfmt;
    if      (off + 256 * MBs <= ws_size) { planA = 1; rfmt = 0; g = 8; }
    else if (off + 192 * MBs <= ws_size) { planA = 1; rfmt = 1; g = 8; }
    else if (off + 128 * MBs <= ws_size) { planA = 1; rfmt = 0; g = 4; }
    else if (off +  96 * MBs <= ws_size) { planA = 1; rfmt = 1; g = 4; }
    else {
        planA = 0; rfmt = 0; g = 2;
        while (g > 1 && off + (size_t)g * 24 * MBs > ws_size) g >>= 1;
    }
    _Float16* Ae = (_Float16*)alloc((size_t)g * CAP * DIM * 2);
    void* routedv = (void*)Ae;                       // alias (see above)
    if (planA && rfmt == 0)
        (void)alloc((size_t)g * CAP * DIM * 2);      // extension: f32 needs 2x
    _Float16* H  = (_Float16*)alloc((size_t)g * CAP * HID * 2);

    hipMemsetAsync(d_out, 0, (size_t)out_size * 4, stream);
    hipMemsetAsync(counters, 0, 256, stream);
    hipMemsetAsync(hist, 0, (size_t)NE * 65536 * 4, stream);
    if (planA) hipMemsetAsync(tokcnt, 0, (size_t)N_TOK * 4, stream);

    router_kernel<<<N_TOK / 4, 256, 0, stream>>>(x, wg, scoresT);
    hist16_kernel<<<dim3(N_TOK / 512, NE), 256, 0, stream>>>(scoresT, hist);
    scan16_kernel<<<NE, 256, 0, stream>>>(hist, prefix16, G16, rem);
    fill_collect_kernel<<<dim3(N_TOK / 256, NE), 256, 0, stream>>>(
        scoresT, prefix16, cnt, candcnt, idx, scale, candbuf);
    cand_rank_kernel<<<NE, 256, 0, stream>>>(prefix16, G16, rem, candcnt, candbuf, idx, scale);
    if (planA)
        inv_build_kernel<<<NE * CAP / 256, 256, 0, stream>>>(idx, tokcnt, toklist);

    // single dispatch: w1 -> even 32-col groups, w3 -> odd, w2 -> plain B^T
    transpose_convert_all_kernel<<<dim3(512, 1, 24), 256, 0, stream>>>(
        w1, w3, w2, w13T, w2T);

    for (int e0 = 0; e0 < NE; e0 += g) {
        gather_rows_kernel<<<dim3(CAP, g), 256, 0, stream>>>(x, idx, scale, Ae, e0);
        gemm13_swiglu_kernel<<<dim3(256 * g), 512, 0, stream>>>(Ae, w13T, H, e0);
        gemm2_scatter_kernel<<<dim3(64 * g), 512, 0, stream>>>(
            H, w2T, out, idx, routedv, e0, (g >= 4) ? 1 : 0, planA, rfmt);
        if (planA)
            combine_kernel<<<N_TOK / 4, 256, 0, stream>>>(
                routedv, tokcnt, toklist, out, e0, g, e0 != 0 ? 1 : 0, rfmt);
    }
}